// Round 5
// baseline (369.930 us; speedup 1.0000x reference)
//
#include <hip/hip_runtime.h>

#define NB 8
#define NNODE 2048
#define NEDGE 65536
#define H 128
#define BM 64
#define SH 68   // u32 stride per LDS row: 64 data + 4 pad -> 272B = 17*16B (b128-aligned)

typedef __attribute__((ext_vector_type(8))) short bf16x8;
typedef __attribute__((ext_vector_type(4))) float f32x4;

union U8 { uint4 u4; bf16x8 s8; };

__device__ __forceinline__ unsigned f32_bf16_rne(float f) {
    unsigned u = __float_as_uint(f);
    return (u + 0x7FFFu + ((u >> 16) & 1u)) >> 16;
}
__device__ __forceinline__ float bf16_f32(unsigned h) {
    return __uint_as_float(h << 16);
}
__device__ __forceinline__ float silu_f(float a) {
    return a / (1.0f + __expf(-a));
}

// ws layout (floats): u1[128] | u2[128] | v[128] | w3 frags (8192 u32 = 32KB)
// frag f = ks*8+nt : lane holds B[k=ks*32+(l>>4)*8+j][col=nt*16+(l&15)], j=0..7,
// packed as 4 u32 (bf16 pairs), stored at w3f[f*256 + lane*4 .. +3]
__global__ __launch_bounds__(64) void precomp_kernel(
    const float* __restrict__ emb_w, const float* __restrict__ emb_b,
    const float* __restrict__ lin_w, const float* __restrict__ lin_b,
    float* __restrict__ ws)
{
    const int bid = blockIdx.x;
    const int t = threadIdx.x;
    if (bid < 32) {
        const int ks = bid >> 3, nt = bid & 7;
        const int g = t >> 4, c = t & 15;
        const int col = nt * 16 + c;
        const float* src = lin_w + col * 384 + 256;
        uint4 w;
        {
            int k0 = ks * 32 + g * 8;
            w.x = f32_bf16_rne(src[k0 + 0]) | (f32_bf16_rne(src[k0 + 1]) << 16);
            w.y = f32_bf16_rne(src[k0 + 2]) | (f32_bf16_rne(src[k0 + 3]) << 16);
            w.z = f32_bf16_rne(src[k0 + 4]) | (f32_bf16_rne(src[k0 + 5]) << 16);
            w.w = f32_bf16_rne(src[k0 + 6]) | (f32_bf16_rne(src[k0 + 7]) << 16);
        }
        unsigned* w3f = (unsigned*)(ws + 384);
        *(uint4*)(w3f + bid * 256 + t * 4) = w;
    } else {
        const int o = (bid - 32) * 64 + t;   // 0..127
        const float* wrow = lin_w + o * 384;
        float u1 = 0.f, u2 = 0.f, v = lin_b[o];
        #pragma unroll 8
        for (int c = 0; c < 128; ++c) {
            float w1 = wrow[c], w2 = wrow[128 + c];
            u1 += emb_w[c] * w1;
            u2 += emb_w[c] * w2;
            v  += emb_b[c] * (w1 + w2);
        }
        ws[o] = u1; ws[128 + o] = u2; ws[256 + o] = v;
    }
}

__global__ __launch_bounds__(256, 4) void edge_kernel(
    const float* __restrict__ x,      // [8*2048]
    const float* __restrict__ rbf,    // [M*6]
    const int*   __restrict__ gi,     // [65536]
    const int*   __restrict__ gj,     // [65536]
    const float* __restrict__ rbf_w,  // [128*6]
    const float* __restrict__ rbf_b,  // [128]
    const float* __restrict__ ws,
    float* __restrict__ out)          // [M*128]
{
    __shared__ unsigned RH[BM * SH];  // 17408 B : bf16-hi pairs of silu'd r
    __shared__ unsigned RL[BM * SH];  // 17408 B : bf16-lo pairs
    __shared__ float rbf_s[BM * 6];   // 1536 B

    const int tid  = threadIdx.x;
    const int wid  = tid >> 6;
    const int lane = tid & 63;
    const int g    = lane >> 4;
    const int c15  = lane & 15;
    const long m0  = (long)blockIdx.x * BM;

    // ---------------- early independent loads (hide latency)
    // stage rbf rows for this block (64 rows x 6 f32 = 96 float4)
    if (tid < 96)
        ((float4*)rbf_s)[tid] = ((const float4*)(rbf + m0 * 6))[tid];

    // edge gathers for the epilogue
    const int ebase = ((int)(blockIdx.x & 1023) << 6) + wid * 16 + g * 4;
    const int4 gi4 = *(const int4*)(gi + ebase);
    const int4 gj4 = *(const int4*)(gj + ebase);
    const float* xb = x + (blockIdx.x >> 10) * NNODE;
    float sr[4], tr[4];
    sr[0] = xb[gi4.x]; sr[1] = xb[gi4.y]; sr[2] = xb[gi4.z]; sr[3] = xb[gi4.w];
    tr[0] = xb[gj4.x]; tr[1] = xb[gj4.y]; tr[2] = xb[gj4.z]; tr[3] = xb[gj4.w];

    // first half-tile of W3 fragments (ks=0, h=0)
    const unsigned* w3f = (const unsigned*)(ws + 384);
    uint4 wf0[4], wf1[4];
    #pragma unroll
    for (int q = 0; q < 4; ++q)
        wf0[q] = *(const uint4*)(w3f + ((0 * 8 + q) * 64 + lane) * 4);

    // ---------------- phase-A weights: 8 adjacent cols c15*8..+7 (48 w + 8 b)
    float wa[48], wb[8];
    {
        const float4* wsrc = (const float4*)(rbf_w + c15 * 48);
        #pragma unroll
        for (int i = 0; i < 12; ++i)
            *(float4*)&wa[i * 4] = wsrc[i];
        *(float4*)&wb[0] = *(const float4*)(rbf_b + c15 * 8);
        *(float4*)&wb[4] = *(const float4*)(rbf_b + c15 * 8 + 4);
    }
    __syncthreads();   // rbf_s ready

    // ---------------- Phase A: r = silu(rbf @ rbf_w.T + b), hi/lo bf16 split into LDS
    #pragma unroll
    for (int r = 0; r < 4; ++r) {
        const int row = wid * 16 + g * 4 + r;
        const float* qq = rbf_s + row * 6;
        const float q0 = qq[0], q1 = qq[1], q2 = qq[2];
        const float q3 = qq[3], q4 = qq[4], q5 = qq[5];
        unsigned hp[4], lp[4];
        #pragma unroll
        for (int p = 0; p < 4; ++p) {
            float y[2];
            #pragma unroll
            for (int s = 0; s < 2; ++s) {
                const int nt = 2 * p + s;
                float d = wb[nt];
                d += q0 * wa[nt * 6 + 0]; d += q1 * wa[nt * 6 + 1];
                d += q2 * wa[nt * 6 + 2]; d += q3 * wa[nt * 6 + 3];
                d += q4 * wa[nt * 6 + 4]; d += q5 * wa[nt * 6 + 5];
                y[s] = silu_f(d);
            }
            const unsigned h0 = f32_bf16_rne(y[0]);
            const unsigned l0 = f32_bf16_rne(y[0] - bf16_f32(h0));
            const unsigned h1 = f32_bf16_rne(y[1]);
            const unsigned l1 = f32_bf16_rne(y[1] - bf16_f32(h1));
            hp[p] = h0 | (h1 << 16);
            lp[p] = l0 | (l1 << 16);
        }
        *(uint4*)&RH[row * SH + c15 * 4] = make_uint4(hp[0], hp[1], hp[2], hp[3]);
        *(uint4*)&RL[row * SH + c15 * 4] = make_uint4(lp[0], lp[1], lp[2], lp[3]);
    }
    __syncthreads();

    // ---------------- Phase B: out[16 x 128] per wave = (Rh + Rl) @ W3h via MFMA
    f32x4 acc4[8];
    #pragma unroll
    for (int nt = 0; nt < 8; ++nt) acc4[nt] = (f32x4){0.f, 0.f, 0.f, 0.f};

    const int arow = wid * 16 + c15;   // A-operand row for this lane

    #pragma unroll
    for (int ks = 0; ks < 4; ++ks) {
        U8 Ah, Al;
        Ah.u4 = *(const uint4*)&RH[arow * SH + ks * 16 + g * 4];
        Al.u4 = *(const uint4*)&RL[arow * SH + ks * 16 + g * 4];

        // prefetch h=1 fragments of this ks
        #pragma unroll
        for (int q = 0; q < 4; ++q)
            wf1[q] = *(const uint4*)(w3f + ((ks * 8 + 4 + q) * 64 + lane) * 4);

        #pragma unroll
        for (int q = 0; q < 4; ++q) {
            U8 B; B.u4 = wf0[q];
            acc4[q] = __builtin_amdgcn_mfma_f32_16x16x32_bf16(Ah.s8, B.s8, acc4[q], 0, 0, 0);
            acc4[q] = __builtin_amdgcn_mfma_f32_16x16x32_bf16(Al.s8, B.s8, acc4[q], 0, 0, 0);
        }

        // prefetch h=0 fragments of next ks
        if (ks < 3) {
            #pragma unroll
            for (int q = 0; q < 4; ++q)
                wf0[q] = *(const uint4*)(w3f + (((ks + 1) * 8 + q) * 64 + lane) * 4);
        }

        #pragma unroll
        for (int q = 0; q < 4; ++q) {
            U8 B; B.u4 = wf1[q];
            acc4[4 + q] = __builtin_amdgcn_mfma_f32_16x16x32_bf16(Ah.s8, B.s8, acc4[4 + q], 0, 0, 0);
            acc4[4 + q] = __builtin_amdgcn_mfma_f32_16x16x32_bf16(Al.s8, B.s8, acc4[4 + q], 0, 0, 0);
        }
    }

    // ---------------- Epilogue: rank-1 + bias + silu + store (D: row=g*4+r, col=nt*16+c15)
    #pragma unroll
    for (int nt = 0; nt < 8; ++nt) {
        const int col = nt * 16 + c15;
        const float u1c = ws[col], u2c = ws[128 + col], vc = ws[256 + col];
        const long mbase = m0 + wid * 16 + g * 4;
        #pragma unroll
        for (int r = 0; r < 4; ++r) {
            float o = acc4[nt][r] + sr[r] * u1c + tr[r] * u2c + vc;
            out[(mbase + r) * H + col] = silu_f(o);
        }
    }
}

extern "C" void kernel_launch(void* const* d_in, const int* in_sizes, int n_in,
                              void* d_out, int out_size, void* d_ws, size_t ws_size,
                              hipStream_t stream) {
    const float* x     = (const float*)d_in[0];
    const float* rbf   = (const float*)d_in[1];
    const int*   gi    = (const int*)  d_in[2];
    const int*   gj    = (const int*)  d_in[3];
    const float* emb_w = (const float*)d_in[4];
    const float* emb_b = (const float*)d_in[5];
    const float* rbf_w = (const float*)d_in[6];
    const float* rbf_b = (const float*)d_in[7];
    const float* lin_w = (const float*)d_in[8];
    const float* lin_b = (const float*)d_in[9];
    float* out = (float*)d_out;
    float* ws  = (float*)d_ws;

    precomp_kernel<<<34, 64, 0, stream>>>(emb_w, emb_b, lin_w, lin_b, ws);

    const int nblocks = (NB * NEDGE) / BM;   // 8192
    edge_kernel<<<nblocks, 256, 0, stream>>>(x, rbf, gi, gj, rbf_w, rbf_b, ws, out);
}

// Round 6
// 367.723 us; speedup vs baseline: 1.0060x; 1.0060x over previous
//
#include <hip/hip_runtime.h>

#define NB 8
#define NNODE 2048
#define NEDGE 65536
#define H 128
#define BM 64
#define SH 68   // u32 stride per LDS row: 64 data + 4 pad -> 272B = 17*16B (b128-aligned)

typedef __attribute__((ext_vector_type(8))) short bf16x8;
typedef __attribute__((ext_vector_type(4))) float f32x4;

union U8 { uint4 u4; bf16x8 s8; };

__device__ __forceinline__ unsigned f32_bf16_rne(float f) {
    unsigned u = __float_as_uint(f);
    return (u + 0x7FFFu + ((u >> 16) & 1u)) >> 16;
}
__device__ __forceinline__ float bf16_f32(unsigned h) {
    return __uint_as_float(h << 16);
}
__device__ __forceinline__ float silu_f(float a) {
    return a / (1.0f + __expf(-a));
}

// ws layout (floats): u1[128] | u2[128] | v[128] | w3 frags (8192 u32 = 32KB)
// frag f = ks*8+nt : lane holds B[k=ks*32+(l>>4)*8+j][globalcol=(l&15)*8+nt], j=0..7,
// packed as 4 u32 (bf16 pairs), stored at w3f[f*256 + lane*4 .. +3].
// Column remap (c*8+nt) makes each lane's 8 D-tiles cover 8 CONSECUTIVE output cols.
__global__ __launch_bounds__(64) void precomp_kernel(
    const float* __restrict__ emb_w, const float* __restrict__ emb_b,
    const float* __restrict__ lin_w, const float* __restrict__ lin_b,
    float* __restrict__ ws)
{
    const int bid = blockIdx.x;
    const int t = threadIdx.x;
    if (bid < 32) {
        const int ks = bid >> 3, nt = bid & 7;
        const int g = t >> 4, c = t & 15;
        const int col = c * 8 + nt;            // remapped global column
        const float* src = lin_w + col * 384 + 256;
        uint4 w;
        {
            int k0 = ks * 32 + g * 8;
            w.x = f32_bf16_rne(src[k0 + 0]) | (f32_bf16_rne(src[k0 + 1]) << 16);
            w.y = f32_bf16_rne(src[k0 + 2]) | (f32_bf16_rne(src[k0 + 3]) << 16);
            w.z = f32_bf16_rne(src[k0 + 4]) | (f32_bf16_rne(src[k0 + 5]) << 16);
            w.w = f32_bf16_rne(src[k0 + 6]) | (f32_bf16_rne(src[k0 + 7]) << 16);
        }
        unsigned* w3f = (unsigned*)(ws + 384);
        *(uint4*)(w3f + bid * 256 + t * 4) = w;
    } else {
        const int o = (bid - 32) * 64 + t;   // 0..127
        const float* wrow = lin_w + o * 384;
        float u1 = 0.f, u2 = 0.f, v = lin_b[o];
        #pragma unroll 8
        for (int c = 0; c < 128; ++c) {
            float w1 = wrow[c], w2 = wrow[128 + c];
            u1 += emb_w[c] * w1;
            u2 += emb_w[c] * w2;
            v  += emb_b[c] * (w1 + w2);
        }
        ws[o] = u1; ws[128 + o] = u2; ws[256 + o] = v;
    }
}

__global__ __launch_bounds__(256, 4) void edge_kernel(
    const float* __restrict__ x,      // [8*2048]
    const float* __restrict__ rbf,    // [M*6]
    const int*   __restrict__ gi,     // [65536]
    const int*   __restrict__ gj,     // [65536]
    const float* __restrict__ rbf_w,  // [128*6]
    const float* __restrict__ rbf_b,  // [128]
    const float* __restrict__ ws,
    float* __restrict__ out)          // [M*128]
{
    __shared__ unsigned RH[BM * SH];  // 17408 B : bf16-hi pairs of silu'd r
    __shared__ unsigned RL[BM * SH];  // 17408 B : bf16-lo pairs
    __shared__ float rbf_s[BM * 6];   // 1536 B

    const int tid  = threadIdx.x;
    const int wid  = tid >> 6;
    const int lane = tid & 63;
    const int g    = lane >> 4;
    const int c15  = lane & 15;
    const long m0  = (long)blockIdx.x * BM;

    // ---------------- early independent loads (hide latency)
    if (tid < 96)
        ((float4*)rbf_s)[tid] = ((const float4*)(rbf + m0 * 6))[tid];

    // edge gathers for the epilogue
    const int ebase = ((int)(blockIdx.x & 1023) << 6) + wid * 16 + g * 4;
    const int4 gi4 = *(const int4*)(gi + ebase);
    const int4 gj4 = *(const int4*)(gj + ebase);
    const float* xb = x + (blockIdx.x >> 10) * NNODE;
    float sr[4], tr[4];
    sr[0] = xb[gi4.x]; sr[1] = xb[gi4.y]; sr[2] = xb[gi4.z]; sr[3] = xb[gi4.w];
    tr[0] = xb[gj4.x]; tr[1] = xb[gj4.y]; tr[2] = xb[gj4.z]; tr[3] = xb[gj4.w];

    // first half-tile of W3 fragments (ks=0, h=0)
    const unsigned* w3f = (const unsigned*)(ws + 384);
    uint4 wf0[4], wf1[4];
    #pragma unroll
    for (int q = 0; q < 4; ++q)
        wf0[q] = *(const uint4*)(w3f + ((0 * 8 + q) * 64 + lane) * 4);

    // ---------------- phase-A weights: 8 adjacent channels c15*8..+7 (48 w + 8 b)
    float wa[48], wb[8];
    {
        const float4* wsrc = (const float4*)(rbf_w + c15 * 48);
        #pragma unroll
        for (int i = 0; i < 12; ++i)
            *(float4*)&wa[i * 4] = wsrc[i];
        *(float4*)&wb[0] = *(const float4*)(rbf_b + c15 * 8);
        *(float4*)&wb[4] = *(const float4*)(rbf_b + c15 * 8 + 4);
    }
    __syncthreads();   // rbf_s ready

    // ---------------- Phase A: r = silu(rbf @ rbf_w.T + b), hi/lo bf16 split into LDS
    #pragma unroll
    for (int r = 0; r < 4; ++r) {
        const int row = wid * 16 + g * 4 + r;
        const float* qq = rbf_s + row * 6;
        const float q0 = qq[0], q1 = qq[1], q2 = qq[2];
        const float q3 = qq[3], q4 = qq[4], q5 = qq[5];
        unsigned hp[4], lp[4];
        #pragma unroll
        for (int p = 0; p < 4; ++p) {
            float y[2];
            #pragma unroll
            for (int s = 0; s < 2; ++s) {
                const int nt = 2 * p + s;
                float d = wb[nt];
                d += q0 * wa[nt * 6 + 0]; d += q1 * wa[nt * 6 + 1];
                d += q2 * wa[nt * 6 + 2]; d += q3 * wa[nt * 6 + 3];
                d += q4 * wa[nt * 6 + 4]; d += q5 * wa[nt * 6 + 5];
                y[s] = silu_f(d);
            }
            const unsigned h0 = f32_bf16_rne(y[0]);
            const unsigned l0 = f32_bf16_rne(y[0] - bf16_f32(h0));
            const unsigned h1 = f32_bf16_rne(y[1]);
            const unsigned l1 = f32_bf16_rne(y[1] - bf16_f32(h1));
            hp[p] = h0 | (h1 << 16);
            lp[p] = l0 | (l1 << 16);
        }
        *(uint4*)&RH[row * SH + c15 * 4] = make_uint4(hp[0], hp[1], hp[2], hp[3]);
        *(uint4*)&RL[row * SH + c15 * 4] = make_uint4(lp[0], lp[1], lp[2], lp[3]);
    }
    __syncthreads();

    // ---------------- Phase B: out[16 x 128] per wave = (Rh + Rl) @ W3h via MFMA
    f32x4 acc4[8];
    #pragma unroll
    for (int nt = 0; nt < 8; ++nt) acc4[nt] = (f32x4){0.f, 0.f, 0.f, 0.f};

    const int arow = wid * 16 + c15;   // A-operand row for this lane

    #pragma unroll
    for (int ks = 0; ks < 4; ++ks) {
        U8 Ah, Al;
        Ah.u4 = *(const uint4*)&RH[arow * SH + ks * 16 + g * 4];
        Al.u4 = *(const uint4*)&RL[arow * SH + ks * 16 + g * 4];

        // prefetch h=1 fragments of this ks
        #pragma unroll
        for (int q = 0; q < 4; ++q)
            wf1[q] = *(const uint4*)(w3f + ((ks * 8 + 4 + q) * 64 + lane) * 4);

        #pragma unroll
        for (int q = 0; q < 4; ++q) {
            U8 B; B.u4 = wf0[q];
            acc4[q] = __builtin_amdgcn_mfma_f32_16x16x32_bf16(Ah.s8, B.s8, acc4[q], 0, 0, 0);
            acc4[q] = __builtin_amdgcn_mfma_f32_16x16x32_bf16(Al.s8, B.s8, acc4[q], 0, 0, 0);
        }

        // prefetch h=0 fragments of next ks
        if (ks < 3) {
            #pragma unroll
            for (int q = 0; q < 4; ++q)
                wf0[q] = *(const uint4*)(w3f + (((ks + 1) * 8 + q) * 64 + lane) * 4);
        }

        #pragma unroll
        for (int q = 0; q < 4; ++q) {
            U8 B; B.u4 = wf1[q];
            acc4[4 + q] = __builtin_amdgcn_mfma_f32_16x16x32_bf16(Ah.s8, B.s8, acc4[4 + q], 0, 0, 0);
            acc4[4 + q] = __builtin_amdgcn_mfma_f32_16x16x32_bf16(Al.s8, B.s8, acc4[4 + q], 0, 0, 0);
        }
    }

    // ---------------- Epilogue: rank-1 + bias + silu + contiguous float4 stores
    // lane's 8 accs at row r are global cols c15*8 .. c15*8+7  (tile nt -> col c15*8+nt)
    const int cb = c15 * 8;
    const float4 U1a = *(const float4*)(ws + cb);
    const float4 U1b = *(const float4*)(ws + cb + 4);
    const float4 U2a = *(const float4*)(ws + 128 + cb);
    const float4 U2b = *(const float4*)(ws + 128 + cb + 4);
    const float4 Va  = *(const float4*)(ws + 256 + cb);
    const float4 Vb  = *(const float4*)(ws + 256 + cb + 4);
    const long mbase = m0 + wid * 16 + g * 4;

    #pragma unroll
    for (int r = 0; r < 4; ++r) {
        const float s = sr[r], t = tr[r];
        float4 oa, ob;
        oa.x = silu_f(acc4[0][r] + s * U1a.x + t * U2a.x + Va.x);
        oa.y = silu_f(acc4[1][r] + s * U1a.y + t * U2a.y + Va.y);
        oa.z = silu_f(acc4[2][r] + s * U1a.z + t * U2a.z + Va.z);
        oa.w = silu_f(acc4[3][r] + s * U1a.w + t * U2a.w + Va.w);
        ob.x = silu_f(acc4[4][r] + s * U1b.x + t * U2b.x + Vb.x);
        ob.y = silu_f(acc4[5][r] + s * U1b.y + t * U2b.y + Vb.y);
        ob.z = silu_f(acc4[6][r] + s * U1b.z + t * U2b.z + Vb.z);
        ob.w = silu_f(acc4[7][r] + s * U1b.w + t * U2b.w + Vb.w);
        float* dst = out + (mbase + r) * H + cb;
        *(float4*)dst = oa;
        *(float4*)(dst + 4) = ob;
    }
}

extern "C" void kernel_launch(void* const* d_in, const int* in_sizes, int n_in,
                              void* d_out, int out_size, void* d_ws, size_t ws_size,
                              hipStream_t stream) {
    const float* x     = (const float*)d_in[0];
    const float* rbf   = (const float*)d_in[1];
    const int*   gi    = (const int*)  d_in[2];
    const int*   gj    = (const int*)  d_in[3];
    const float* emb_w = (const float*)d_in[4];
    const float* emb_b = (const float*)d_in[5];
    const float* rbf_w = (const float*)d_in[6];
    const float* rbf_b = (const float*)d_in[7];
    const float* lin_w = (const float*)d_in[8];
    const float* lin_b = (const float*)d_in[9];
    float* out = (float*)d_out;
    float* ws  = (float*)d_ws;

    precomp_kernel<<<34, 64, 0, stream>>>(emb_w, emb_b, lin_w, lin_b, ws);

    const int nblocks = (NB * NEDGE) / BM;   // 8192
    edge_kernel<<<nblocks, 256, 0, stream>>>(x, rbf, gi, gj, rbf_w, rbf_b, ws, out);
}